// Round 6
// baseline (692.292 us; speedup 1.0000x reference)
//
#include <hip/hip_runtime.h>
#include <climits>

#define D 128

typedef float f32x4 __attribute__((ext_vector_type(4)));

// ---------------- CSR build step 1: histogram ----------------
__global__ __launch_bounds__(256) void hist_kernel(const int* __restrict__ erow,
                                                   int* __restrict__ deg, int nE) {
    int e = blockIdx.x * 256 + threadIdx.x;
    if (e < nE) atomicAdd(&deg[erow[e]], 1);
}

// ---------------- scan phase 1: per-block (1024 elems) inclusive scan ----------------
__global__ __launch_bounds__(256) void scan1_kernel(const int* __restrict__ deg,
                                                    int* __restrict__ rowptr,
                                                    int* __restrict__ blocksums, int n) {
    __shared__ int sd[256];
    const int t = threadIdx.x;
    const int idx = blockIdx.x * 1024 + t * 4;
    int4 v = make_int4(0, 0, 0, 0);
    if (idx + 3 < n) v = *(const int4*)&deg[idx];
    else {
        if (idx + 0 < n) v.x = deg[idx + 0];
        if (idx + 1 < n) v.y = deg[idx + 1];
        if (idx + 2 < n) v.z = deg[idx + 2];
        if (idx + 3 < n) v.w = deg[idx + 3];
    }
    const int s = v.x + v.y + v.z + v.w;
    sd[t] = s;
    __syncthreads();
    for (int off = 1; off < 256; off <<= 1) {
        int tv = (t >= off) ? sd[t - off] : 0;
        __syncthreads();
        sd[t] += tv;
        __syncthreads();
    }
    const int excl = sd[t] - s;
    int a = excl + v.x, b = a + v.y, c = b + v.z, d = c + v.w;
    if (idx + 0 < n) rowptr[idx + 1] = a;
    if (idx + 1 < n) rowptr[idx + 2] = b;
    if (idx + 2 < n) rowptr[idx + 3] = c;
    if (idx + 3 < n) rowptr[idx + 4] = d;
    if (t == 255) blocksums[blockIdx.x] = sd[255];
}

// ---------------- scan phase 2: exclusive scan of block sums (nb <= 256) ----------------
__global__ __launch_bounds__(256) void scan2_kernel(int* __restrict__ blocksums, int nb) {
    __shared__ int sd[256];
    const int t = threadIdx.x;
    const int v = (t < nb) ? blocksums[t] : 0;
    sd[t] = v;
    __syncthreads();
    for (int off = 1; off < 256; off <<= 1) {
        int tv = (t >= off) ? sd[t - off] : 0;
        __syncthreads();
        sd[t] += tv;
        __syncthreads();
    }
    if (t < nb) blocksums[t] = sd[t] - v;   // exclusive
}

// ---------------- scan phase 3: add block offsets; finalize rowptr ----------------
__global__ __launch_bounds__(256) void scan3_kernel(int* __restrict__ rowptr,
                                                    const int* __restrict__ blocksums, int n) {
    int i = blockIdx.x * 256 + threadIdx.x;
    if (i < n) rowptr[i + 1] += blocksums[i >> 10];
    if (i == 0) rowptr[0] = 0;
}

// ---------------- CSR build: placement (slot order nondeterministic) ----------------
__global__ __launch_bounds__(256) void place_kernel(const int* __restrict__ erow,
                                                    const int* __restrict__ rowptr,
                                                    int* __restrict__ fill,
                                                    int* __restrict__ slots, int nE) {
    int e = blockIdx.x * 256 + threadIdx.x;
    if (e >= nE) return;
    int r = erow[e];
    int pos = rowptr[r] + atomicAdd(&fill[r], 1);
    slots[pos] = e;   // edge index; canonicalized by sortrow_wave
}

// ---- canonicalize + gather: wave rank-sort of each row's edge indices, then fetch col/val ----
__global__ __launch_bounds__(256) void sortrow_wave_kernel(const int* __restrict__ rowptr,
                                                           int* __restrict__ cols_s,
                                                           float* __restrict__ vals_s,
                                                           const int* __restrict__ ecol,
                                                           const float* __restrict__ ev, int n) {
    int row = blockIdx.x * 4 + (threadIdx.x >> 6);
    if (row >= n) return;
    const int lane = threadIdx.x & 63;
    const int s = rowptr[row], e = rowptr[row + 1];
    const int deg = e - s;
    if (deg <= 0) return;
    if (deg <= 64) {
        int v = (lane < deg) ? cols_s[s + lane] : INT_MAX;
        int rank = 0;
        for (int i = 0; i < deg; ++i) {
            int vi = __shfl(v, i);
            rank += (vi < v) ? 1 : 0;
        }
        if (lane < deg) {                       // wave-lockstep: all reads precede writes
            cols_s[s + rank] = ecol[v];
            vals_s[s + rank] = ev[v];
        }
    } else if (lane == 0) {                     // ~never (deg ~ Poisson(16))
        for (int i = s + 1; i < e; ++i) {
            int key = cols_s[i];
            int j = i - 1;
            while (j >= s && cols_s[j] > key) { cols_s[j + 1] = cols_s[j]; --j; }
            cols_s[j + 1] = key;
        }
        for (int i = s; i < e; ++i) {
            int eidx = cols_s[i];
            cols_s[i] = ecol[eidx];
            vals_s[i] = ev[eidx];
        }
    }
}

// ---------------- pull SpMM: t[row] = sum_k val[k] * h[col[k]] ----------------
// 32 lanes x float4 per row; 2 rows per wave; unroll 8 -> deep MLP.
// nontemporal on cols/vals (stream) and t (write-once) to keep h LLC-resident.
__global__ __launch_bounds__(256) void spmm_pull_kernel(const float* __restrict__ h,
                                                        const int* __restrict__ rowptr,
                                                        const int* __restrict__ cols,
                                                        const float* __restrict__ vals,
                                                        float* __restrict__ t, int n) {
    int r = blockIdx.x * 8 + (threadIdx.x >> 5);
    if (r >= n) return;
    const int l = threadIdx.x & 31;
    const f32x4* hl = (const f32x4*)h + l;
    const int s = rowptr[r], e = rowptr[r + 1];
    f32x4 acc = (f32x4)(0.f);
    int k = s;
    for (; k + 8 <= e; k += 8) {
        int c[8];
        float v[8];
#pragma unroll
        for (int u = 0; u < 8; ++u) {
            c[u] = __builtin_nontemporal_load(&cols[k + u]);
            v[u] = __builtin_nontemporal_load(&vals[k + u]);
        }
        f32x4 hv[8];
#pragma unroll
        for (int u = 0; u < 8; ++u) hv[u] = hl[(size_t)c[u] * 32];
#pragma unroll
        for (int u = 0; u < 8; ++u) acc += v[u] * hv[u];
    }
    for (; k + 4 <= e; k += 4) {
        int c0 = cols[k], c1 = cols[k + 1], c2 = cols[k + 2], c3 = cols[k + 3];
        float v0 = vals[k], v1 = vals[k + 1], v2 = vals[k + 2], v3 = vals[k + 3];
        f32x4 h0 = hl[(size_t)c0 * 32];
        f32x4 h1 = hl[(size_t)c1 * 32];
        f32x4 h2 = hl[(size_t)c2 * 32];
        f32x4 h3 = hl[(size_t)c3 * 32];
        acc += v0 * h0;
        acc += v1 * h1;
        acc += v2 * h2;
        acc += v3 * h3;
    }
    for (; k < e; ++k) {
        int c = cols[k];
        float v = vals[k];
        f32x4 hv = hl[(size_t)c * 32];
        acc += v * hv;
    }
    __builtin_nontemporal_store(acc, (f32x4*)t + (size_t)r * 32 + l);
}

// ---------------- O = relu(A @ W), A: n x 128, W: 128 x 128 ----------------
__global__ __launch_bounds__(256) void gemm_relu_kernel(const float* __restrict__ A,
                                                        const float* __restrict__ W,
                                                        float* __restrict__ O, int n) {
    __shared__ float ws[D * D];
    for (int i = threadIdx.x * 4; i < D * D; i += 256 * 4)
        *(float4*)&ws[i] = *(const float4*)&W[i];
    __syncthreads();

    const int cg = threadIdx.x & 7;    // 8 col groups of 16
    const int rq = threadIdx.x >> 3;   // 32 row quads
    const int row0 = blockIdx.x * 128 + rq * 4;
    const int c0 = cg * 16;

    float acc[4][16];
#pragma unroll
    for (int r = 0; r < 4; ++r)
#pragma unroll
        for (int c = 0; c < 16; ++c) acc[r][c] = 0.f;

    for (int k = 0; k < D; k += 4) {
        float4 a[4];
#pragma unroll
        for (int r = 0; r < 4; ++r) {
            int row = row0 + r;
            a[r] = (row < n) ? *(const float4*)&A[(size_t)row * D + k]
                             : make_float4(0.f, 0.f, 0.f, 0.f);
        }
#pragma unroll
        for (int kk = 0; kk < 4; ++kk) {
            const float* wrow = &ws[(k + kk) * D + c0];
            float4 w0 = *(const float4*)&wrow[0];
            float4 w1 = *(const float4*)&wrow[4];
            float4 w2 = *(const float4*)&wrow[8];
            float4 w3 = *(const float4*)&wrow[12];
#pragma unroll
            for (int r = 0; r < 4; ++r) {
                float av = (&a[r].x)[kk];
                acc[r][0]  += av * w0.x;  acc[r][1]  += av * w0.y;
                acc[r][2]  += av * w0.z;  acc[r][3]  += av * w0.w;
                acc[r][4]  += av * w1.x;  acc[r][5]  += av * w1.y;
                acc[r][6]  += av * w1.z;  acc[r][7]  += av * w1.w;
                acc[r][8]  += av * w2.x;  acc[r][9]  += av * w2.y;
                acc[r][10] += av * w2.z;  acc[r][11] += av * w2.w;
                acc[r][12] += av * w3.x;  acc[r][13] += av * w3.y;
                acc[r][14] += av * w3.z;  acc[r][15] += av * w3.w;
            }
        }
    }

#pragma unroll
    for (int r = 0; r < 4; ++r) {
        int row = row0 + r;
        if (row >= n) continue;
        float* o = &O[(size_t)row * D + c0];
#pragma unroll
        for (int g = 0; g < 4; ++g) {
            float4 v;
            v.x = fmaxf(acc[r][g * 4 + 0], 0.f);
            v.y = fmaxf(acc[r][g * 4 + 1], 0.f);
            v.z = fmaxf(acc[r][g * 4 + 2], 0.f);
            v.w = fmaxf(acc[r][g * 4 + 3], 0.f);
            *(float4*)&o[g * 4] = v;
        }
    }
}

// ---------------- out = (H @ Cls > 0) ? 1 : 0, Cls: 128 x 16 ----------------
__global__ __launch_bounds__(256) void classify_kernel(const float* __restrict__ H,
                                                       const float* __restrict__ Cls,
                                                       float* __restrict__ out, int n) {
    __shared__ float cs[D * 16];
    for (int i = threadIdx.x * 4; i < D * 16; i += 256 * 4)
        *(float4*)&cs[i] = *(const float4*)&Cls[i];
    __syncthreads();

    int row = blockIdx.x * 256 + threadIdx.x;
    if (row >= n) return;

    float acc[16];
#pragma unroll
    for (int j = 0; j < 16; ++j) acc[j] = 0.f;

    for (int k = 0; k < D; k += 4) {
        float4 h = *(const float4*)&H[(size_t)row * D + k];
#pragma unroll
        for (int kk = 0; kk < 4; ++kk) {
            float hv = (&h.x)[kk];
            const float* crow = &cs[(k + kk) * 16];
#pragma unroll
            for (int j = 0; j < 16; ++j) acc[j] += hv * crow[j];
        }
    }

    float* o = &out[(size_t)row * 16];
#pragma unroll
    for (int g = 0; g < 4; ++g) {
        float4 v;
        v.x = acc[g * 4 + 0] > 0.f ? 1.f : 0.f;
        v.y = acc[g * 4 + 1] > 0.f ? 1.f : 0.f;
        v.z = acc[g * 4 + 2] > 0.f ? 1.f : 0.f;
        v.w = acc[g * 4 + 3] > 0.f ? 1.f : 0.f;
        *(float4*)&o[g * 4] = v;
    }
}

extern "C" void kernel_launch(void* const* d_in, const int* in_sizes, int n_in,
                              void* d_out, int out_size, void* d_ws, size_t ws_size,
                              hipStream_t stream) {
    const float* x    = (const float*)d_in[0];
    const int*   erow = (const int*)d_in[1];
    const int*   ecol = (const int*)d_in[2];
    const float* ev   = (const float*)d_in[3];
    const float* w1   = (const float*)d_in[4];
    const float* w2   = (const float*)d_in[5];
    const float* cls  = (const float*)d_in[6];

    const int n  = in_sizes[0] / D;   // 100000
    const int nE = in_sizes[1];       // 1600000

    // workspace layout
    char* ws = (char*)d_ws;
    float* t      = (float*)ws;                 ws += (size_t)n * D * 4;   // 51.2 MB
    float* h      = (float*)ws;                 ws += (size_t)n * D * 4;   // 51.2 MB
    int*   deg    = (int*)ws;                   ws += (size_t)n * 4;
    int*   rowptr = (int*)ws;                   ws += (size_t)(n + 1) * 4;
    int*   fill   = (int*)ws;                   ws += (size_t)n * 4;
    int*   cols_s = (int*)ws;                   ws += (size_t)nE * 4;      // slots -> cols
    float* vals_s = (float*)ws;                 ws += (size_t)nE * 4;
    int*   bsums  = (int*)ws;                   ws += 256 * 4;

    const int nb = (n + 1023) / 1024;   // 98 <= 256

    dim3 blk(256);
    dim3 egrid((nE + 255) / 256);
    dim3 ngrid((n + 255) / 256);
    dim3 wgrid((n + 3) / 4);      // 1 wave per row kernels
    dim3 sgrid((n + 7) / 8);      // spmm: 8 rows per block
    dim3 ggrid((n + 127) / 128);

    // ---- CSR build (deterministic) ----
    (void)hipMemsetAsync(deg, 0, (size_t)n * 4, stream);
    (void)hipMemsetAsync(fill, 0, (size_t)n * 4, stream);
    hist_kernel<<<egrid, blk, 0, stream>>>(erow, deg, nE);
    scan1_kernel<<<nb, blk, 0, stream>>>(deg, rowptr, bsums, n);
    scan2_kernel<<<1, blk, 0, stream>>>(bsums, nb);
    scan3_kernel<<<ngrid, blk, 0, stream>>>(rowptr, bsums, n);
    place_kernel<<<egrid, blk, 0, stream>>>(erow, rowptr, fill, cols_s, nE);
    sortrow_wave_kernel<<<wgrid, blk, 0, stream>>>(rowptr, cols_s, vals_s, ecol, ev, n);

    // ---- layer 1 ----
    spmm_pull_kernel<<<sgrid, blk, 0, stream>>>(x, rowptr, cols_s, vals_s, t, n);
    gemm_relu_kernel<<<ggrid, blk, 0, stream>>>(t, w1, h, n);

    // ---- layer 2 ----
    spmm_pull_kernel<<<sgrid, blk, 0, stream>>>(h, rowptr, cols_s, vals_s, t, n);
    gemm_relu_kernel<<<ggrid, blk, 0, stream>>>(t, w2, h, n);

    // ---- classifier + hard threshold ----
    classify_kernel<<<ngrid, blk, 0, stream>>>(h, cls, (float*)d_out, n);
}

// Round 7
// 639.717 us; speedup vs baseline: 1.0822x; 1.0822x over previous
//
#include <hip/hip_runtime.h>
#include <climits>

#define D 128

typedef float f32x4 __attribute__((ext_vector_type(4)));

// ---- CSR step 1: histogram + per-edge arrival rank (rank is call-varying; sort canonicalizes) ----
__global__ __launch_bounds__(256) void hist_rank_kernel(const int* __restrict__ erow,
                                                        int* __restrict__ deg,
                                                        int* __restrict__ rank, int nE) {
    int e = blockIdx.x * 256 + threadIdx.x;
    if (e < nE) rank[e] = atomicAdd(&deg[erow[e]], 1);
}

// ---- scan phase 1: per-block (1024 elems) inclusive scan ----
__global__ __launch_bounds__(256) void scan1_kernel(const int* __restrict__ deg,
                                                    int* __restrict__ rowptr,
                                                    int* __restrict__ blocksums, int n) {
    __shared__ int sd[256];
    const int t = threadIdx.x;
    const int idx = blockIdx.x * 1024 + t * 4;
    int4 v = make_int4(0, 0, 0, 0);
    if (idx + 3 < n) v = *(const int4*)&deg[idx];
    else {
        if (idx + 0 < n) v.x = deg[idx + 0];
        if (idx + 1 < n) v.y = deg[idx + 1];
        if (idx + 2 < n) v.z = deg[idx + 2];
        if (idx + 3 < n) v.w = deg[idx + 3];
    }
    const int s = v.x + v.y + v.z + v.w;
    sd[t] = s;
    __syncthreads();
    for (int off = 1; off < 256; off <<= 1) {
        int tv = (t >= off) ? sd[t - off] : 0;
        __syncthreads();
        sd[t] += tv;
        __syncthreads();
    }
    const int excl = sd[t] - s;
    int a = excl + v.x, b = a + v.y, c = b + v.z, d = c + v.w;
    if (idx + 0 < n) rowptr[idx + 1] = a;
    if (idx + 1 < n) rowptr[idx + 2] = b;
    if (idx + 2 < n) rowptr[idx + 3] = c;
    if (idx + 3 < n) rowptr[idx + 4] = d;
    if (t == 255) blocksums[blockIdx.x] = sd[255];
}

// ---- scan phase 2: exclusive scan of block sums (nb <= 256) ----
__global__ __launch_bounds__(256) void scan2_kernel(int* __restrict__ blocksums, int nb) {
    __shared__ int sd[256];
    const int t = threadIdx.x;
    const int v = (t < nb) ? blocksums[t] : 0;
    sd[t] = v;
    __syncthreads();
    for (int off = 1; off < 256; off <<= 1) {
        int tv = (t >= off) ? sd[t - off] : 0;
        __syncthreads();
        sd[t] += tv;
        __syncthreads();
    }
    if (t < nb) blocksums[t] = sd[t] - v;   // exclusive
}

// ---- scan phase 3: add block offsets; finalize rowptr ----
__global__ __launch_bounds__(256) void scan3_kernel(int* __restrict__ rowptr,
                                                    const int* __restrict__ blocksums, int n) {
    int i = blockIdx.x * 256 + threadIdx.x;
    if (i < n) rowptr[i + 1] += blocksums[i >> 10];
    if (i == 0) rowptr[0] = 0;
}

// ---- CSR placement: NO atomics, all reads coalesced; 3 scattered 4B stores (L2-absorbed) ----
__global__ __launch_bounds__(256) void place_kernel(const int* __restrict__ erow,
                                                    const int* __restrict__ rank,
                                                    const int* __restrict__ ecol,
                                                    const float* __restrict__ ev,
                                                    const int* __restrict__ rowptr,
                                                    int* __restrict__ eidx_s,
                                                    int* __restrict__ cols_s,
                                                    float* __restrict__ vals_s, int nE) {
    int e = blockIdx.x * 256 + threadIdx.x;
    if (e >= nE) return;
    int pos = rowptr[erow[e]] + rank[e];
    eidx_s[pos] = e;
    cols_s[pos] = ecol[e];
    vals_s[pos] = ev[e];
}

// ---- canonicalize: wave rank-sort each row's triples by edge idx (reads coalesced in-row) ----
__global__ __launch_bounds__(256) void sortrow_wave_kernel(const int* __restrict__ rowptr,
                                                           int* __restrict__ eidx_s,
                                                           int* __restrict__ cols_s,
                                                           float* __restrict__ vals_s, int n) {
    int row = blockIdx.x * 4 + (threadIdx.x >> 6);
    if (row >= n) return;
    const int lane = threadIdx.x & 63;
    const int s = rowptr[row], e = rowptr[row + 1];
    const int deg = e - s;
    if (deg <= 0) return;
    if (deg <= 64) {
        int key = INT_MAX, col = 0;
        float val = 0.f;
        if (lane < deg) {
            key = eidx_s[s + lane];
            col = cols_s[s + lane];
            val = vals_s[s + lane];
        }
        int rank = 0;
        for (int i = 0; i < deg; ++i) {
            int ki = __shfl(key, i);
            rank += (ki < key) ? 1 : 0;
        }
        if (lane < deg) {                   // wave-lockstep: all reads above precede writes
            cols_s[s + rank] = col;
            vals_s[s + rank] = val;
        }
    } else if (lane == 0) {                 // deg>64: ~never (deg ~ Poisson(16))
        for (int i = s + 1; i < e; ++i) {
            int k_ = eidx_s[i], c_ = cols_s[i];
            float v_ = vals_s[i];
            int j = i - 1;
            while (j >= s && eidx_s[j] > k_) {
                eidx_s[j + 1] = eidx_s[j];
                cols_s[j + 1] = cols_s[j];
                vals_s[j + 1] = vals_s[j];
                --j;
            }
            eidx_s[j + 1] = k_;
            cols_s[j + 1] = c_;
            vals_s[j + 1] = v_;
        }
    }
}

// ---- pull SpMM: t[row] = sum_k val[k] * h[col[k]]; 32 lanes x float4, 2 rows/wave, unroll 8 ----
__global__ __launch_bounds__(256) void spmm_pull_kernel(const float* __restrict__ h,
                                                        const int* __restrict__ rowptr,
                                                        const int* __restrict__ cols,
                                                        const float* __restrict__ vals,
                                                        float* __restrict__ t, int n) {
    int r = blockIdx.x * 8 + (threadIdx.x >> 5);
    if (r >= n) return;
    const int l = threadIdx.x & 31;
    const f32x4* hl = (const f32x4*)h + l;
    const int s = rowptr[r], e = rowptr[r + 1];
    f32x4 acc = (f32x4)(0.f);
    int k = s;
    for (; k + 8 <= e; k += 8) {
        int c[8];
        float v[8];
#pragma unroll
        for (int u = 0; u < 8; ++u) {
            c[u] = __builtin_nontemporal_load(&cols[k + u]);
            v[u] = __builtin_nontemporal_load(&vals[k + u]);
        }
        f32x4 hv[8];
#pragma unroll
        for (int u = 0; u < 8; ++u) hv[u] = hl[(size_t)c[u] * 32];
#pragma unroll
        for (int u = 0; u < 8; ++u) acc += v[u] * hv[u];
    }
    for (; k + 4 <= e; k += 4) {
        int c0 = cols[k], c1 = cols[k + 1], c2 = cols[k + 2], c3 = cols[k + 3];
        float v0 = vals[k], v1 = vals[k + 1], v2 = vals[k + 2], v3 = vals[k + 3];
        f32x4 h0 = hl[(size_t)c0 * 32];
        f32x4 h1 = hl[(size_t)c1 * 32];
        f32x4 h2 = hl[(size_t)c2 * 32];
        f32x4 h3 = hl[(size_t)c3 * 32];
        acc += v0 * h0;
        acc += v1 * h1;
        acc += v2 * h2;
        acc += v3 * h3;
    }
    for (; k < e; ++k) {
        int c = cols[k];
        float v = vals[k];
        f32x4 hv = hl[(size_t)c * 32];
        acc += v * hv;
    }
    __builtin_nontemporal_store(acc, (f32x4*)t + (size_t)r * 32 + l);
}

// ---------------- O = relu(A @ W), A: n x 128, W: 128 x 128 ----------------
__global__ __launch_bounds__(256) void gemm_relu_kernel(const float* __restrict__ A,
                                                        const float* __restrict__ W,
                                                        float* __restrict__ O, int n) {
    __shared__ float ws[D * D];
    for (int i = threadIdx.x * 4; i < D * D; i += 256 * 4)
        *(float4*)&ws[i] = *(const float4*)&W[i];
    __syncthreads();

    const int cg = threadIdx.x & 7;    // 8 col groups of 16
    const int rq = threadIdx.x >> 3;   // 32 row quads
    const int row0 = blockIdx.x * 128 + rq * 4;
    const int c0 = cg * 16;

    float acc[4][16];
#pragma unroll
    for (int r = 0; r < 4; ++r)
#pragma unroll
        for (int c = 0; c < 16; ++c) acc[r][c] = 0.f;

    for (int k = 0; k < D; k += 4) {
        float4 a[4];
#pragma unroll
        for (int r = 0; r < 4; ++r) {
            int row = row0 + r;
            a[r] = (row < n) ? *(const float4*)&A[(size_t)row * D + k]
                             : make_float4(0.f, 0.f, 0.f, 0.f);
        }
#pragma unroll
        for (int kk = 0; kk < 4; ++kk) {
            const float* wrow = &ws[(k + kk) * D + c0];
            float4 w0 = *(const float4*)&wrow[0];
            float4 w1 = *(const float4*)&wrow[4];
            float4 w2 = *(const float4*)&wrow[8];
            float4 w3 = *(const float4*)&wrow[12];
#pragma unroll
            for (int r = 0; r < 4; ++r) {
                float av = (&a[r].x)[kk];
                acc[r][0]  += av * w0.x;  acc[r][1]  += av * w0.y;
                acc[r][2]  += av * w0.z;  acc[r][3]  += av * w0.w;
                acc[r][4]  += av * w1.x;  acc[r][5]  += av * w1.y;
                acc[r][6]  += av * w1.z;  acc[r][7]  += av * w1.w;
                acc[r][8]  += av * w2.x;  acc[r][9]  += av * w2.y;
                acc[r][10] += av * w2.z;  acc[r][11] += av * w2.w;
                acc[r][12] += av * w3.x;  acc[r][13] += av * w3.y;
                acc[r][14] += av * w3.z;  acc[r][15] += av * w3.w;
            }
        }
    }

#pragma unroll
    for (int r = 0; r < 4; ++r) {
        int row = row0 + r;
        if (row >= n) continue;
        float* o = &O[(size_t)row * D + c0];
#pragma unroll
        for (int g = 0; g < 4; ++g) {
            float4 v;
            v.x = fmaxf(acc[r][g * 4 + 0], 0.f);
            v.y = fmaxf(acc[r][g * 4 + 1], 0.f);
            v.z = fmaxf(acc[r][g * 4 + 2], 0.f);
            v.w = fmaxf(acc[r][g * 4 + 3], 0.f);
            *(float4*)&o[g * 4] = v;
        }
    }
}

// ---------------- out = (H @ Cls > 0) ? 1 : 0, Cls: 128 x 16 ----------------
__global__ __launch_bounds__(256) void classify_kernel(const float* __restrict__ H,
                                                       const float* __restrict__ Cls,
                                                       float* __restrict__ out, int n) {
    __shared__ float cs[D * 16];
    for (int i = threadIdx.x * 4; i < D * 16; i += 256 * 4)
        *(float4*)&cs[i] = *(const float4*)&Cls[i];
    __syncthreads();

    int row = blockIdx.x * 256 + threadIdx.x;
    if (row >= n) return;

    float acc[16];
#pragma unroll
    for (int j = 0; j < 16; ++j) acc[j] = 0.f;

    for (int k = 0; k < D; k += 4) {
        float4 h = *(const float4*)&H[(size_t)row * D + k];
#pragma unroll
        for (int kk = 0; kk < 4; ++kk) {
            float hv = (&h.x)[kk];
            const float* crow = &cs[(k + kk) * 16];
#pragma unroll
            for (int j = 0; j < 16; ++j) acc[j] += hv * crow[j];
        }
    }

    float* o = &out[(size_t)row * 16];
#pragma unroll
    for (int g = 0; g < 4; ++g) {
        float4 v;
        v.x = acc[g * 4 + 0] > 0.f ? 1.f : 0.f;
        v.y = acc[g * 4 + 1] > 0.f ? 1.f : 0.f;
        v.z = acc[g * 4 + 2] > 0.f ? 1.f : 0.f;
        v.w = acc[g * 4 + 3] > 0.f ? 1.f : 0.f;
        *(float4*)&o[g * 4] = v;
    }
}

extern "C" void kernel_launch(void* const* d_in, const int* in_sizes, int n_in,
                              void* d_out, int out_size, void* d_ws, size_t ws_size,
                              hipStream_t stream) {
    const float* x    = (const float*)d_in[0];
    const int*   erow = (const int*)d_in[1];
    const int*   ecol = (const int*)d_in[2];
    const float* ev   = (const float*)d_in[3];
    const float* w1   = (const float*)d_in[4];
    const float* w2   = (const float*)d_in[5];
    const float* cls  = (const float*)d_in[6];

    const int n  = in_sizes[0] / D;   // 100000
    const int nE = in_sizes[1];       // 1600000

    // workspace layout
    char* ws = (char*)d_ws;
    float* t      = (float*)ws;                 ws += (size_t)n * D * 4;   // 51.2 MB
    float* h      = (float*)ws;                 ws += (size_t)n * D * 4;   // 51.2 MB
    int*   deg    = (int*)ws;                   ws += (size_t)n * 4;
    int*   rowptr = (int*)ws;                   ws += (size_t)(n + 1) * 4;
    int*   rank   = (int*)ws;                   ws += (size_t)nE * 4;
    int*   eidx_s = (int*)ws;                   ws += (size_t)nE * 4;
    int*   cols_s = (int*)ws;                   ws += (size_t)nE * 4;
    float* vals_s = (float*)ws;                 ws += (size_t)nE * 4;
    int*   bsums  = (int*)ws;                   ws += 256 * 4;

    const int nb = (n + 1023) / 1024;   // 98 <= 256

    dim3 blk(256);
    dim3 egrid((nE + 255) / 256);
    dim3 ngrid((n + 255) / 256);
    dim3 wgrid((n + 3) / 4);      // 1 wave per row kernels
    dim3 sgrid((n + 7) / 8);      // spmm: 8 rows per block
    dim3 ggrid((n + 127) / 128);

    // ---- CSR build (deterministic final order; zero random loads) ----
    (void)hipMemsetAsync(deg, 0, (size_t)n * 4, stream);
    hist_rank_kernel<<<egrid, blk, 0, stream>>>(erow, deg, rank, nE);
    scan1_kernel<<<nb, blk, 0, stream>>>(deg, rowptr, bsums, n);
    scan2_kernel<<<1, blk, 0, stream>>>(bsums, nb);
    scan3_kernel<<<ngrid, blk, 0, stream>>>(rowptr, bsums, n);
    place_kernel<<<egrid, blk, 0, stream>>>(erow, rank, ecol, ev, rowptr,
                                            eidx_s, cols_s, vals_s, nE);
    sortrow_wave_kernel<<<wgrid, blk, 0, stream>>>(rowptr, eidx_s, cols_s, vals_s, n);

    // ---- layer 1 ----
    spmm_pull_kernel<<<sgrid, blk, 0, stream>>>(x, rowptr, cols_s, vals_s, t, n);
    gemm_relu_kernel<<<ggrid, blk, 0, stream>>>(t, w1, h, n);

    // ---- layer 2 ----
    spmm_pull_kernel<<<sgrid, blk, 0, stream>>>(h, rowptr, cols_s, vals_s, t, n);
    gemm_relu_kernel<<<ggrid, blk, 0, stream>>>(t, w2, h, n);

    // ---- classifier + hard threshold ----
    classify_kernel<<<ngrid, blk, 0, stream>>>(h, cls, (float*)d_out, n);
}

// Round 8
// 617.007 us; speedup vs baseline: 1.1220x; 1.0368x over previous
//
#include <hip/hip_runtime.h>
#include <climits>

#define D 128

typedef float f32x4 __attribute__((ext_vector_type(4)));
typedef int   i32x2 __attribute__((ext_vector_type(2)));

// ---- CSR step 1: histogram + per-edge arrival rank (rank call-varying; sort canonicalizes) ----
__global__ __launch_bounds__(256) void hist_rank_kernel(const int* __restrict__ erow,
                                                        int* __restrict__ deg,
                                                        int* __restrict__ rank, int nE) {
    int e = blockIdx.x * 256 + threadIdx.x;
    if (e < nE) rank[e] = atomicAdd(&deg[erow[e]], 1);
}

// ---- scan phase 1: per-block (1024 elems) inclusive scan ----
__global__ __launch_bounds__(256) void scan1_kernel(const int* __restrict__ deg,
                                                    int* __restrict__ rowptr,
                                                    int* __restrict__ blocksums, int n) {
    __shared__ int sd[256];
    const int t = threadIdx.x;
    const int idx = blockIdx.x * 1024 + t * 4;
    int4 v = make_int4(0, 0, 0, 0);
    if (idx + 3 < n) v = *(const int4*)&deg[idx];
    else {
        if (idx + 0 < n) v.x = deg[idx + 0];
        if (idx + 1 < n) v.y = deg[idx + 1];
        if (idx + 2 < n) v.z = deg[idx + 2];
        if (idx + 3 < n) v.w = deg[idx + 3];
    }
    const int s = v.x + v.y + v.z + v.w;
    sd[t] = s;
    __syncthreads();
    for (int off = 1; off < 256; off <<= 1) {
        int tv = (t >= off) ? sd[t - off] : 0;
        __syncthreads();
        sd[t] += tv;
        __syncthreads();
    }
    const int excl = sd[t] - s;
    int a = excl + v.x, b = a + v.y, c = b + v.z, d = c + v.w;
    if (idx + 0 < n) rowptr[idx + 1] = a;
    if (idx + 1 < n) rowptr[idx + 2] = b;
    if (idx + 2 < n) rowptr[idx + 3] = c;
    if (idx + 3 < n) rowptr[idx + 4] = d;
    if (t == 255) blocksums[blockIdx.x] = sd[255];
}

// ---- scan phase 2: exclusive scan of block sums (nb <= 256) ----
__global__ __launch_bounds__(256) void scan2_kernel(int* __restrict__ blocksums, int nb) {
    __shared__ int sd[256];
    const int t = threadIdx.x;
    const int v = (t < nb) ? blocksums[t] : 0;
    sd[t] = v;
    __syncthreads();
    for (int off = 1; off < 256; off <<= 1) {
        int tv = (t >= off) ? sd[t - off] : 0;
        __syncthreads();
        sd[t] += tv;
        __syncthreads();
    }
    if (t < nb) blocksums[t] = sd[t] - v;   // exclusive
}

// ---- scan phase 3: add block offsets; finalize rowptr ----
__global__ __launch_bounds__(256) void scan3_kernel(int* __restrict__ rowptr,
                                                    const int* __restrict__ blocksums, int n) {
    int i = blockIdx.x * 256 + threadIdx.x;
    if (i < n) rowptr[i + 1] += blocksums[i >> 10];
    if (i == 0) rowptr[0] = 0;
}

// ---- CSR placement: one packed 8B record {col, valbits} per edge; no atomics ----
__global__ __launch_bounds__(256) void place_kernel(const int* __restrict__ erow,
                                                    const int* __restrict__ rank,
                                                    const int* __restrict__ ecol,
                                                    const float* __restrict__ ev,
                                                    const int* __restrict__ rowptr,
                                                    i32x2* __restrict__ cv, int nE) {
    int e = blockIdx.x * 256 + threadIdx.x;
    if (e >= nE) return;
    int pos = rowptr[erow[e]] + rank[e];
    i32x2 rec;
    rec.x = ecol[e];
    rec.y = __float_as_int(ev[e]);
    cv[pos] = rec;
}

// ---- canonicalize: wave rank-sort each row's records by u64(col,valbits) ----
// ties are content-identical records -> any tie-break yields the same final array (deterministic)
__global__ __launch_bounds__(256) void sortrow_wave_kernel(const int* __restrict__ rowptr,
                                                           i32x2* __restrict__ cv, int n) {
    int row = blockIdx.x * 4 + (threadIdx.x >> 6);
    if (row >= n) return;
    const int lane = threadIdx.x & 63;
    const int s = rowptr[row], e = rowptr[row + 1];
    const int deg = e - s;
    if (deg <= 1) return;
    if (deg <= 64) {
        unsigned long long key = ~0ull;
        i32x2 rec;
        rec.x = 0; rec.y = 0;
        if (lane < deg) {
            rec = cv[s + lane];
            key = ((unsigned long long)(unsigned)rec.x << 32) | (unsigned)rec.y;
        }
        int rank = 0;
        for (int i = 0; i < deg; ++i) {
            unsigned long long ki = __shfl(key, i);
            rank += (ki < key || (ki == key && i < lane)) ? 1 : 0;
        }
        if (lane < deg) cv[s + rank] = rec;   // wave-lockstep: reads precede writes
    } else if (lane == 0) {                   // deg>64: ~never (deg ~ Poisson(16))
        for (int i = s + 1; i < e; ++i) {
            i32x2 r_ = cv[i];
            unsigned long long k_ = ((unsigned long long)(unsigned)r_.x << 32) | (unsigned)r_.y;
            int j = i - 1;
            while (j >= s) {
                i32x2 rj = cv[j];
                unsigned long long kj = ((unsigned long long)(unsigned)rj.x << 32) | (unsigned)rj.y;
                if (kj <= k_) break;
                cv[j + 1] = rj;
                --j;
            }
            cv[j + 1] = r_;
        }
    }
}

// ---- pull SpMM: t[row] = sum_k val[k]*h[col[k]]; 32 lanes x float4, 2 rows/wave, unroll 8 ----
__global__ __launch_bounds__(256) void spmm_pull_kernel(const float* __restrict__ h,
                                                        const int* __restrict__ rowptr,
                                                        const i32x2* __restrict__ cv,
                                                        float* __restrict__ t, int n) {
    int r = blockIdx.x * 8 + (threadIdx.x >> 5);
    if (r >= n) return;
    const int l = threadIdx.x & 31;
    const f32x4* hl = (const f32x4*)h + l;
    const int s = rowptr[r], e = rowptr[r + 1];
    f32x4 acc = (f32x4)(0.f);
    int k = s;
    for (; k + 8 <= e; k += 8) {
        i32x2 p[8];
#pragma unroll
        for (int u = 0; u < 8; ++u) p[u] = __builtin_nontemporal_load(&cv[k + u]);
        f32x4 hv[8];
#pragma unroll
        for (int u = 0; u < 8; ++u) hv[u] = hl[(size_t)p[u].x * 32];
#pragma unroll
        for (int u = 0; u < 8; ++u) acc += __int_as_float(p[u].y) * hv[u];
    }
    for (; k < e; ++k) {
        i32x2 p = __builtin_nontemporal_load(&cv[k]);
        f32x4 hv = hl[(size_t)p.x * 32];
        acc += __int_as_float(p.y) * hv;
    }
    __builtin_nontemporal_store(acc, (f32x4*)t + (size_t)r * 32 + l);
}

// ---------------- O = relu(A @ W), A: n x 128, W: 128 x 128 ----------------
__global__ __launch_bounds__(256) void gemm_relu_kernel(const float* __restrict__ A,
                                                        const float* __restrict__ W,
                                                        float* __restrict__ O, int n) {
    __shared__ float ws[D * D];
    for (int i = threadIdx.x * 4; i < D * D; i += 256 * 4)
        *(float4*)&ws[i] = *(const float4*)&W[i];
    __syncthreads();

    const int cg = threadIdx.x & 7;    // 8 col groups of 16
    const int rq = threadIdx.x >> 3;   // 32 row quads
    const int row0 = blockIdx.x * 128 + rq * 4;
    const int c0 = cg * 16;

    float acc[4][16];
#pragma unroll
    for (int r = 0; r < 4; ++r)
#pragma unroll
        for (int c = 0; c < 16; ++c) acc[r][c] = 0.f;

    for (int k = 0; k < D; k += 4) {
        float4 a[4];
#pragma unroll
        for (int r = 0; r < 4; ++r) {
            int row = row0 + r;
            a[r] = (row < n) ? *(const float4*)&A[(size_t)row * D + k]
                             : make_float4(0.f, 0.f, 0.f, 0.f);
        }
#pragma unroll
        for (int kk = 0; kk < 4; ++kk) {
            const float* wrow = &ws[(k + kk) * D + c0];
            float4 w0 = *(const float4*)&wrow[0];
            float4 w1 = *(const float4*)&wrow[4];
            float4 w2 = *(const float4*)&wrow[8];
            float4 w3 = *(const float4*)&wrow[12];
#pragma unroll
            for (int r = 0; r < 4; ++r) {
                float av = (&a[r].x)[kk];
                acc[r][0]  += av * w0.x;  acc[r][1]  += av * w0.y;
                acc[r][2]  += av * w0.z;  acc[r][3]  += av * w0.w;
                acc[r][4]  += av * w1.x;  acc[r][5]  += av * w1.y;
                acc[r][6]  += av * w1.z;  acc[r][7]  += av * w1.w;
                acc[r][8]  += av * w2.x;  acc[r][9]  += av * w2.y;
                acc[r][10] += av * w2.z;  acc[r][11] += av * w2.w;
                acc[r][12] += av * w3.x;  acc[r][13] += av * w3.y;
                acc[r][14] += av * w3.z;  acc[r][15] += av * w3.w;
            }
        }
    }

#pragma unroll
    for (int r = 0; r < 4; ++r) {
        int row = row0 + r;
        if (row >= n) continue;
        float* o = &O[(size_t)row * D + c0];
#pragma unroll
        for (int g = 0; g < 4; ++g) {
            float4 v;
            v.x = fmaxf(acc[r][g * 4 + 0], 0.f);
            v.y = fmaxf(acc[r][g * 4 + 1], 0.f);
            v.z = fmaxf(acc[r][g * 4 + 2], 0.f);
            v.w = fmaxf(acc[r][g * 4 + 3], 0.f);
            *(float4*)&o[g * 4] = v;
        }
    }
}

// ---------------- out = (H @ Cls > 0) ? 1 : 0, Cls: 128 x 16 ----------------
__global__ __launch_bounds__(256) void classify_kernel(const float* __restrict__ H,
                                                       const float* __restrict__ Cls,
                                                       float* __restrict__ out, int n) {
    __shared__ float cs[D * 16];
    for (int i = threadIdx.x * 4; i < D * 16; i += 256 * 4)
        *(float4*)&cs[i] = *(const float4*)&Cls[i];
    __syncthreads();

    int row = blockIdx.x * 256 + threadIdx.x;
    if (row >= n) return;

    float acc[16];
#pragma unroll
    for (int j = 0; j < 16; ++j) acc[j] = 0.f;

    for (int k = 0; k < D; k += 4) {
        float4 h = *(const float4*)&H[(size_t)row * D + k];
#pragma unroll
        for (int kk = 0; kk < 4; ++kk) {
            float hv = (&h.x)[kk];
            const float* crow = &cs[(k + kk) * 16];
#pragma unroll
            for (int j = 0; j < 16; ++j) acc[j] += hv * crow[j];
        }
    }

    float* o = &out[(size_t)row * 16];
#pragma unroll
    for (int g = 0; g < 4; ++g) {
        float4 v;
        v.x = acc[g * 4 + 0] > 0.f ? 1.f : 0.f;
        v.y = acc[g * 4 + 1] > 0.f ? 1.f : 0.f;
        v.z = acc[g * 4 + 2] > 0.f ? 1.f : 0.f;
        v.w = acc[g * 4 + 3] > 0.f ? 1.f : 0.f;
        *(float4*)&o[g * 4] = v;
    }
}

extern "C" void kernel_launch(void* const* d_in, const int* in_sizes, int n_in,
                              void* d_out, int out_size, void* d_ws, size_t ws_size,
                              hipStream_t stream) {
    const float* x    = (const float*)d_in[0];
    const int*   erow = (const int*)d_in[1];
    const int*   ecol = (const int*)d_in[2];
    const float* ev   = (const float*)d_in[3];
    const float* w1   = (const float*)d_in[4];
    const float* w2   = (const float*)d_in[5];
    const float* cls  = (const float*)d_in[6];

    const int n  = in_sizes[0] / D;   // 100000
    const int nE = in_sizes[1];       // 1600000

    // workspace layout
    char*  ws     = (char*)d_ws;
    float* t      = (float*)ws;                 ws += (size_t)n * D * 4;   // 51.2 MB
    float* h      = (float*)ws;                 ws += (size_t)n * D * 4;   // 51.2 MB
    int*   deg    = (int*)ws;                   ws += (size_t)n * 4;
    int*   rowptr = (int*)ws;                   ws += (size_t)(n + 1) * 4;
    int*   rank   = (int*)ws;                   ws += (size_t)nE * 4;
    i32x2* cv     = (i32x2*)ws;                 ws += (size_t)nE * 8;      // packed col+val
    int*   bsums  = (int*)ws;                   ws += 256 * 4;

    const int nb = (n + 1023) / 1024;   // 98 <= 256

    dim3 blk(256);
    dim3 egrid((nE + 255) / 256);
    dim3 ngrid((n + 255) / 256);
    dim3 wgrid((n + 3) / 4);      // 1 wave per row kernels
    dim3 sgrid((n + 7) / 8);      // spmm: 8 rows per block
    dim3 ggrid((n + 127) / 128);

    // ---- CSR build (deterministic final order by (col,valbits)) ----
    (void)hipMemsetAsync(deg, 0, (size_t)n * 4, stream);
    hist_rank_kernel<<<egrid, blk, 0, stream>>>(erow, deg, rank, nE);
    scan1_kernel<<<nb, blk, 0, stream>>>(deg, rowptr, bsums, n);
    scan2_kernel<<<1, blk, 0, stream>>>(bsums, nb);
    scan3_kernel<<<ngrid, blk, 0, stream>>>(rowptr, bsums, n);
    place_kernel<<<egrid, blk, 0, stream>>>(erow, rank, ecol, ev, rowptr, cv, nE);
    sortrow_wave_kernel<<<wgrid, blk, 0, stream>>>(rowptr, cv, n);

    // ---- layer 1 ----
    spmm_pull_kernel<<<sgrid, blk, 0, stream>>>(x, rowptr, cv, t, n);
    gemm_relu_kernel<<<ggrid, blk, 0, stream>>>(t, w1, h, n);

    // ---- layer 2 ----
    spmm_pull_kernel<<<sgrid, blk, 0, stream>>>(h, rowptr, cv, t, n);
    gemm_relu_kernel<<<ggrid, blk, 0, stream>>>(t, w2, h, n);

    // ---- classifier + hard threshold ----
    classify_kernel<<<ngrid, blk, 0, stream>>>(h, cls, (float*)d_out, n);
}

// Round 9
// 479.641 us; speedup vs baseline: 1.4434x; 1.2864x over previous
//
#include <hip/hip_runtime.h>
#include <climits>

#define D 128

typedef float f32x4 __attribute__((ext_vector_type(4)));
typedef int   i32x2 __attribute__((ext_vector_type(2)));

// ---- CSR step 1: histogram + per-edge arrival rank (rank call-varying; sort canonicalizes) ----
__global__ __launch_bounds__(256) void hist_rank_kernel(const int* __restrict__ erow,
                                                        int* __restrict__ deg,
                                                        int* __restrict__ rank, int nE) {
    int e = blockIdx.x * 256 + threadIdx.x;
    if (e < nE) rank[e] = atomicAdd(&deg[erow[e]], 1);
}

// ---- scan phase 1: per-block (1024 elems) inclusive scan ----
__global__ __launch_bounds__(256) void scan1_kernel(const int* __restrict__ deg,
                                                    int* __restrict__ rowptr,
                                                    int* __restrict__ blocksums, int n) {
    __shared__ int sd[256];
    const int t = threadIdx.x;
    const int idx = blockIdx.x * 1024 + t * 4;
    int4 v = make_int4(0, 0, 0, 0);
    if (idx + 3 < n) v = *(const int4*)&deg[idx];
    else {
        if (idx + 0 < n) v.x = deg[idx + 0];
        if (idx + 1 < n) v.y = deg[idx + 1];
        if (idx + 2 < n) v.z = deg[idx + 2];
        if (idx + 3 < n) v.w = deg[idx + 3];
    }
    const int s = v.x + v.y + v.z + v.w;
    sd[t] = s;
    __syncthreads();
    for (int off = 1; off < 256; off <<= 1) {
        int tv = (t >= off) ? sd[t - off] : 0;
        __syncthreads();
        sd[t] += tv;
        __syncthreads();
    }
    const int excl = sd[t] - s;
    int a = excl + v.x, b = a + v.y, c = b + v.z, d = c + v.w;
    if (idx + 0 < n) rowptr[idx + 1] = a;
    if (idx + 1 < n) rowptr[idx + 2] = b;
    if (idx + 2 < n) rowptr[idx + 3] = c;
    if (idx + 3 < n) rowptr[idx + 4] = d;
    if (t == 255) blocksums[blockIdx.x] = sd[255];
}

// ---- scan phase 2: exclusive scan of block sums (nb <= 256) ----
__global__ __launch_bounds__(256) void scan2_kernel(int* __restrict__ blocksums, int nb) {
    __shared__ int sd[256];
    const int t = threadIdx.x;
    const int v = (t < nb) ? blocksums[t] : 0;
    sd[t] = v;
    __syncthreads();
    for (int off = 1; off < 256; off <<= 1) {
        int tv = (t >= off) ? sd[t - off] : 0;
        __syncthreads();
        sd[t] += tv;
        __syncthreads();
    }
    if (t < nb) blocksums[t] = sd[t] - v;   // exclusive
}

// ---- scan phase 3: add block offsets; finalize rowptr ----
__global__ __launch_bounds__(256) void scan3_kernel(int* __restrict__ rowptr,
                                                    const int* __restrict__ blocksums, int n) {
    int i = blockIdx.x * 256 + threadIdx.x;
    if (i < n) rowptr[i + 1] += blocksums[i >> 10];
    if (i == 0) rowptr[0] = 0;
}

// ---- CSR placement: one packed 8B record {col, valbits} per edge; no atomics ----
__global__ __launch_bounds__(256) void place_kernel(const int* __restrict__ erow,
                                                    const int* __restrict__ rank,
                                                    const int* __restrict__ ecol,
                                                    const float* __restrict__ ev,
                                                    const int* __restrict__ rowptr,
                                                    i32x2* __restrict__ cv, int nE) {
    int e = blockIdx.x * 256 + threadIdx.x;
    if (e >= nE) return;
    int pos = rowptr[erow[e]] + rank[e];
    i32x2 rec;
    rec.x = ecol[e];
    rec.y = __float_as_int(ev[e]);
    cv[pos] = rec;
}

// ---- canonicalize: wave rank-sort each row's records by u64(col,valbits) ----
__global__ __launch_bounds__(256) void sortrow_wave_kernel(const int* __restrict__ rowptr,
                                                           i32x2* __restrict__ cv, int n) {
    int row = blockIdx.x * 4 + (threadIdx.x >> 6);
    if (row >= n) return;
    const int lane = threadIdx.x & 63;
    const int s = rowptr[row], e = rowptr[row + 1];
    const int deg = e - s;
    if (deg <= 1) return;
    if (deg <= 64) {
        unsigned long long key = ~0ull;
        i32x2 rec;
        rec.x = 0; rec.y = 0;
        if (lane < deg) {
            rec = cv[s + lane];
            key = ((unsigned long long)(unsigned)rec.x << 32) | (unsigned)rec.y;
        }
        int rank = 0;
        for (int i = 0; i < deg; ++i) {
            unsigned long long ki = __shfl(key, i);
            rank += (ki < key || (ki == key && i < lane)) ? 1 : 0;
        }
        if (lane < deg) cv[s + rank] = rec;   // wave-lockstep: reads precede writes
    } else if (lane == 0) {                   // deg>64: ~never (deg ~ Poisson(16))
        for (int i = s + 1; i < e; ++i) {
            i32x2 r_ = cv[i];
            unsigned long long k_ = ((unsigned long long)(unsigned)r_.x << 32) | (unsigned)r_.y;
            int j = i - 1;
            while (j >= s) {
                i32x2 rj = cv[j];
                unsigned long long kj = ((unsigned long long)(unsigned)rj.x << 32) | (unsigned)rj.y;
                if (kj <= k_) break;
                cv[j + 1] = rj;
                --j;
            }
            cv[j + 1] = r_;
        }
    }
}

// ---- fused layer: [gather 64-row tile into LDS] -> [tile @ W, relu] -> h or classify ----
// CLASSIFY=0: writes relu(spmm@W) rows to O.  CLASSIFY=1: also does @Cls > 0 -> out, h not written.
template <bool CLASSIFY>
__global__ __launch_bounds__(256, 4) void fused_layer_kernel(
        const float* __restrict__ h, const int* __restrict__ rowptr,
        const i32x2* __restrict__ cv, const float* __restrict__ W,
        const float* __restrict__ Cls, float* __restrict__ O, int n) {
    __shared__ float tile[64 * D];                       // 32 KB
    __shared__ float cls_s[CLASSIFY ? D * 16 : 1];       // 8 KB when classifying

    if (CLASSIFY) {
        for (int i = threadIdx.x * 8; i < D * 16; i += 256 * 8) {
            *(f32x4*)&cls_s[i]     = *(const f32x4*)&Cls[i];
            *(f32x4*)&cls_s[i + 4] = *(const f32x4*)&Cls[i + 4];
        }
    }

    const int row0 = blockIdx.x * 64;

    // ---- phase 1: gather (pull SpMM) into LDS tile ----
    {
        const int wv = threadIdx.x >> 6;          // wave 0..3
        const int half = (threadIdx.x >> 5) & 1;  // 2 rows per wave per iter
        const int l = threadIdx.x & 31;
        const f32x4* hl = (const f32x4*)h + l;
        for (int i = 0; i < 8; ++i) {
            const int rl = wv * 16 + i * 2 + half;   // local row 0..63
            const int r = row0 + rl;
            f32x4 acc = (f32x4)(0.f);
            if (r < n) {
                const int s = rowptr[r], e = rowptr[r + 1];
                int k = s;
                for (; k + 8 <= e; k += 8) {
                    i32x2 p[8];
#pragma unroll
                    for (int u = 0; u < 8; ++u) p[u] = cv[k + u];
                    f32x4 hv[8];
#pragma unroll
                    for (int u = 0; u < 8; ++u) hv[u] = hl[(size_t)p[u].x * 32];
#pragma unroll
                    for (int u = 0; u < 8; ++u) acc += __int_as_float(p[u].y) * hv[u];
                }
                for (; k < e; ++k) {
                    i32x2 p = cv[k];
                    acc += __int_as_float(p.y) * hl[(size_t)p.x * 32];
                }
            }
            *(f32x4*)&tile[rl * D + l * 4] = acc;
        }
    }
    __syncthreads();

    // ---- phase 2: tile(64x128) @ W(128x128), relu; 4 rows x 8 cols per thread ----
    const int cg = threadIdx.x & 15;    // 16 col groups of 8
    const int rq = threadIdx.x >> 4;    // 16 row quads
    const int c0 = cg * 8;

    float acc[4][8];
#pragma unroll
    for (int r = 0; r < 4; ++r)
#pragma unroll
        for (int c = 0; c < 8; ++c) acc[r][c] = 0.f;

    for (int k = 0; k < D; k += 4) {
        f32x4 a[4];
#pragma unroll
        for (int r = 0; r < 4; ++r) a[r] = *(const f32x4*)&tile[(rq * 4 + r) * D + k];
#pragma unroll
        for (int kk = 0; kk < 4; ++kk) {
            const float* wrow = &W[(k + kk) * D + c0];
            f32x4 w0 = *(const f32x4*)&wrow[0];
            f32x4 w1 = *(const f32x4*)&wrow[4];
#pragma unroll
            for (int r = 0; r < 4; ++r) {
                float av = a[r][kk];
                acc[r][0] += av * w0.x; acc[r][1] += av * w0.y;
                acc[r][2] += av * w0.z; acc[r][3] += av * w0.w;
                acc[r][4] += av * w1.x; acc[r][5] += av * w1.y;
                acc[r][6] += av * w1.z; acc[r][7] += av * w1.w;
            }
        }
    }

    if (!CLASSIFY) {
        // write h rows
#pragma unroll
        for (int r = 0; r < 4; ++r) {
            int row = row0 + rq * 4 + r;
            if (row >= n) continue;
            f32x4 v0, v1;
            v0.x = fmaxf(acc[r][0], 0.f); v0.y = fmaxf(acc[r][1], 0.f);
            v0.z = fmaxf(acc[r][2], 0.f); v0.w = fmaxf(acc[r][3], 0.f);
            v1.x = fmaxf(acc[r][4], 0.f); v1.y = fmaxf(acc[r][5], 0.f);
            v1.z = fmaxf(acc[r][6], 0.f); v1.w = fmaxf(acc[r][7], 0.f);
            *(f32x4*)&O[(size_t)row * D + c0]     = v0;
            *(f32x4*)&O[(size_t)row * D + c0 + 4] = v1;
        }
    } else {
        // overwrite tile with relu(h), then classify from LDS
        __syncthreads();
#pragma unroll
        for (int r = 0; r < 4; ++r) {
            f32x4 v0, v1;
            v0.x = fmaxf(acc[r][0], 0.f); v0.y = fmaxf(acc[r][1], 0.f);
            v0.z = fmaxf(acc[r][2], 0.f); v0.w = fmaxf(acc[r][3], 0.f);
            v1.x = fmaxf(acc[r][4], 0.f); v1.y = fmaxf(acc[r][5], 0.f);
            v1.z = fmaxf(acc[r][6], 0.f); v1.w = fmaxf(acc[r][7], 0.f);
            *(f32x4*)&tile[(rq * 4 + r) * D + c0]     = v0;
            *(f32x4*)&tile[(rq * 4 + r) * D + c0 + 4] = v1;
        }
        __syncthreads();
        // phase 3: 64 rows x 16 classes; 4 logits per thread
        const int rl = threadIdx.x >> 2;       // 0..63
        const int q = threadIdx.x & 3;         // class quad
        float lg[4] = {0.f, 0.f, 0.f, 0.f};
        for (int k = 0; k < D; ++k) {
            float hv = tile[rl * D + k];
            f32x4 c = *(const f32x4*)&cls_s[k * 16 + q * 4];
            lg[0] += hv * c.x; lg[1] += hv * c.y;
            lg[2] += hv * c.z; lg[3] += hv * c.w;
        }
        int row = row0 + rl;
        if (row < n) {
            f32x4 o;
            o.x = lg[0] > 0.f ? 1.f : 0.f;
            o.y = lg[1] > 0.f ? 1.f : 0.f;
            o.z = lg[2] > 0.f ? 1.f : 0.f;
            o.w = lg[3] > 0.f ? 1.f : 0.f;
            *(f32x4*)&O[(size_t)row * 16 + q * 4] = o;
        }
    }
}

extern "C" void kernel_launch(void* const* d_in, const int* in_sizes, int n_in,
                              void* d_out, int out_size, void* d_ws, size_t ws_size,
                              hipStream_t stream) {
    const float* x    = (const float*)d_in[0];
    const int*   erow = (const int*)d_in[1];
    const int*   ecol = (const int*)d_in[2];
    const float* ev   = (const float*)d_in[3];
    const float* w1   = (const float*)d_in[4];
    const float* w2   = (const float*)d_in[5];
    const float* cls  = (const float*)d_in[6];

    const int n  = in_sizes[0] / D;   // 100000
    const int nE = in_sizes[1];       // 1600000

    // workspace layout (t eliminated)
    char*  ws     = (char*)d_ws;
    float* h      = (float*)ws;                 ws += (size_t)n * D * 4;   // 51.2 MB
    int*   deg    = (int*)ws;                   ws += (size_t)n * 4;
    int*   rowptr = (int*)ws;                   ws += (size_t)(n + 1) * 4;
    int*   rank   = (int*)ws;                   ws += (size_t)nE * 4;
    i32x2* cv     = (i32x2*)ws;                 ws += (size_t)nE * 8;      // packed col+val
    int*   bsums  = (int*)ws;                   ws += 256 * 4;

    const int nb = (n + 1023) / 1024;   // 98 <= 256

    dim3 blk(256);
    dim3 egrid((nE + 255) / 256);
    dim3 ngrid((n + 255) / 256);
    dim3 wgrid((n + 3) / 4);      // sortrow: 1 wave per row
    dim3 fgrid((n + 63) / 64);    // fused layers: 64 rows per block

    // ---- CSR build (deterministic final order by (col,valbits)) ----
    (void)hipMemsetAsync(deg, 0, (size_t)n * 4, stream);
    hist_rank_kernel<<<egrid, blk, 0, stream>>>(erow, deg, rank, nE);
    scan1_kernel<<<nb, blk, 0, stream>>>(deg, rowptr, bsums, n);
    scan2_kernel<<<1, blk, 0, stream>>>(bsums, nb);
    scan3_kernel<<<ngrid, blk, 0, stream>>>(rowptr, bsums, n);
    place_kernel<<<egrid, blk, 0, stream>>>(erow, rank, ecol, ev, rowptr, cv, nE);
    sortrow_wave_kernel<<<wgrid, blk, 0, stream>>>(rowptr, cv, n);

    // ---- layer 1: h = relu(spmm(x) @ w1) ----
    fused_layer_kernel<false><<<fgrid, blk, 0, stream>>>(x, rowptr, cv, w1, nullptr, h, n);

    // ---- layer 2 + classifier: out = (relu(spmm(h) @ w2) @ cls > 0) ----
    fused_layer_kernel<true><<<fgrid, blk, 0, stream>>>(h, rowptr, cv, w2, cls,
                                                        (float*)d_out, n);
}